// Round 1
// baseline (413.458 us; speedup 1.0000x reference)
//
#include <hip/hip_runtime.h>
#include <hip/hip_bf16.h>

typedef __attribute__((ext_vector_type(4))) float f32x4;
typedef __attribute__((ext_vector_type(8))) short s16x8;
using bf16 = __hip_bfloat16;

static constexpr int BB  = 4;
static constexpr int SQ  = 512;
static constexpr int SKV = 2048;
static constexpr int SKT = 512;
static constexpr int DIM = 1024;
static constexpr int NH  = 16;
static constexpr int HD  = 64;

__device__ __forceinline__ float b2f(short s) {
  unsigned int u = ((unsigned int)(unsigned short)s) << 16;
  float f; __builtin_memcpy(&f, &u, 4); return f;
}

__device__ __forceinline__ void gload16(const void* g, void* l) {
  __builtin_amdgcn_global_load_lds(
      (const __attribute__((address_space(1))) void*)g,
      (__attribute__((address_space(3))) void*)l, 16, 0, 0);
}

// ---------------- weight cast f32 -> bf16 (batched via grid.y) --------------
struct CastArgs { const float* src[10]; bf16* dst[10]; int n[10]; };
__global__ __launch_bounds__(256) void cast_kernel(CastArgs a) {
  const int y = blockIdx.y;
  const int n = a.n[y];
  const int i = (blockIdx.x * 256 + threadIdx.x) * 4;
  if (i >= n) return;
  const float4 v = *(const float4*)(a.src[y] + i);
  bf16* d = a.dst[y] + i;
  d[0] = __float2bfloat16(v.x); d[1] = __float2bfloat16(v.y);
  d[2] = __float2bfloat16(v.z); d[3] = __float2bfloat16(v.w);
}

// ---------------- RMSNorm (f32 in, bf16 out), one block per row -------------
struct NormArgs { const float* x[3]; const float* w[3]; bf16* y[3]; int rows[3]; };
__global__ __launch_bounds__(256) void rmsnorm_kernel(NormArgs a) {
  const int t = blockIdx.y, row = blockIdx.x;
  if (row >= a.rows[t]) return;
  const float* x = a.x[t] + (size_t)row * DIM;
  const float4 v = *(const float4*)(x + threadIdx.x * 4);
  float ss = v.x*v.x + v.y*v.y + v.z*v.z + v.w*v.w;
  #pragma unroll
  for (int m = 32; m >= 1; m >>= 1) ss += __shfl_xor(ss, m);
  __shared__ float red[4];
  if ((threadIdx.x & 63) == 0) red[threadIdx.x >> 6] = ss;
  __syncthreads();
  ss = red[0] + red[1] + red[2] + red[3];
  const float sc = rsqrtf(ss * (1.0f / DIM) + 1.1920928955078125e-07f);
  const float4 w = *(const float4*)(a.w[t] + threadIdx.x * 4);
  bf16* y = a.y[t] + (size_t)row * DIM + threadIdx.x * 4;
  y[0] = __float2bfloat16(v.x * sc * w.x);
  y[1] = __float2bfloat16(v.y * sc * w.y);
  y[2] = __float2bfloat16(v.z * sc * w.z);
  y[3] = __float2bfloat16(v.w * sc * w.w);
}

// ---------------- GEMM: C = act(A @ W^T + bias) ------------------------------
// A [M,1024] bf16 row-major, W [1024,1024] bf16 row-major (N x K).
// EPI 0: bf16 out; 1: silu -> bf16 out; 2: f32 out + residual.
// 128x128 tile, BK=32, 4 waves (2x2), 4x4 MFMA 16x16x32 per wave.
template<int EPI>
__global__ __launch_bounds__(256) void gemm128(
    const bf16* __restrict__ A, const bf16* __restrict__ W,
    const float* __restrict__ bias, const float* __restrict__ resid,
    bf16* __restrict__ Cb, float* __restrict__ Cf)
{
  constexpr int K = DIM;
  __shared__ alignas(16) short sA[128 * 32];
  __shared__ alignas(16) short sB[128 * 32];
  const int tid = threadIdx.x, lane = tid & 63, wave = tid >> 6;
  const int bm = blockIdx.x, bn = blockIdx.y;
  const int wm = wave >> 1, wn = wave & 1;
  const int m16 = lane & 15, g16 = lane >> 4;

  f32x4 acc[4][4];
  #pragma unroll
  for (int i = 0; i < 4; ++i)
    #pragma unroll
    for (int j = 0; j < 4; ++j)
      #pragma unroll
      for (int r = 0; r < 4; ++r) acc[i][j][r] = 0.0f;

  const bf16* Ab = A + (size_t)bm * 128 * K;
  const bf16* Wb = W + (size_t)bn * 128 * K;
  const int lrow = lane >> 2, lcol = (lane & 3) * 8;

  for (int k0 = 0; k0 < K; k0 += 32) {
    #pragma unroll
    for (int h = 0; h < 2; ++h) {
      const int c = h * 4 + wave;                 // wave-uniform chunk id
      const int row = c * 16 + lrow;              // per-lane global row
      gload16(Ab + (size_t)row * K + k0 + lcol, (char*)sA + c * 1024);
      gload16(Wb + (size_t)row * K + k0 + lcol, (char*)sB + c * 1024);
    }
    __syncthreads();
    s16x8 af[4], bfr[4];
    #pragma unroll
    for (int mi = 0; mi < 4; ++mi)
      af[mi] = *(const s16x8*)(sA + (wm*64 + mi*16 + m16) * 32 + g16 * 8);
    #pragma unroll
    for (int ni = 0; ni < 4; ++ni)
      bfr[ni] = *(const s16x8*)(sB + (wn*64 + ni*16 + m16) * 32 + g16 * 8);
    #pragma unroll
    for (int mi = 0; mi < 4; ++mi)
      #pragma unroll
      for (int ni = 0; ni < 4; ++ni)
        acc[mi][ni] = __builtin_amdgcn_mfma_f32_16x16x32_bf16(
            af[mi], bfr[ni], acc[mi][ni], 0, 0, 0);
    __syncthreads();
  }

  const int r0 = bm*128 + wm*64, c0 = bn*128 + wn*64;
  #pragma unroll
  for (int ni = 0; ni < 4; ++ni) {
    const int col = c0 + ni*16 + m16;
    const float bv = bias[col];
    #pragma unroll
    for (int mi = 0; mi < 4; ++mi) {
      const int rowb = r0 + mi*16 + g16*4;
      #pragma unroll
      for (int r = 0; r < 4; ++r) {
        float v = acc[mi][ni][r] + bv;
        const size_t idx = (size_t)(rowb + r) * DIM + col;
        if (EPI == 1) { v = v / (1.0f + __expf(-v)); Cb[idx] = __float2bfloat16(v); }
        else if (EPI == 2) { Cf[idx] = v + resid[idx]; }
        else { Cb[idx] = __float2bfloat16(v); }
      }
    }
  }
}

// ---------------- gate GEMV: gate = sigmoid(g1 . w2 + b2), wave per row -----
__global__ __launch_bounds__(256) void gate_kernel(
    const bf16* __restrict__ g1, const bf16* __restrict__ w2,
    const float* __restrict__ b2, float* __restrict__ gate, int rows)
{
  const int lane = threadIdx.x & 63, wave = threadIdx.x >> 6;
  const int row = blockIdx.x * 4 + wave;
  if (row >= rows) return;
  const bf16* x = g1 + (size_t)row * DIM;
  float sum = 0.0f;
  #pragma unroll
  for (int c = 0; c < 2; ++c) {
    const int i0 = c * 512 + lane * 8;
    const s16x8 xv = *(const s16x8*)(x + i0);
    const s16x8 wv = *(const s16x8*)(w2 + i0);
    #pragma unroll
    for (int j = 0; j < 8; ++j) sum += b2f(xv[j]) * b2f(wv[j]);
  }
  #pragma unroll
  for (int m = 32; m >= 1; m >>= 1) sum += __shfl_xor(sum, m);
  if (lane == 0) gate[row] = 1.0f / (1.0f + __expf(-(sum + b2[0])));
}

// ---------------- V transpose: [B,Sk,H,64] -> [B*H,64,Sk] --------------------
__global__ __launch_bounds__(256) void vtrans_kernel(
    const bf16* __restrict__ V, bf16* __restrict__ VT, int Sk)
{
  __shared__ alignas(16) short tile[64][72];
  const int kt = blockIdx.x, h = blockIdx.y, b = blockIdx.z;
  const int tid = threadIdx.x;
  #pragma unroll
  for (int i = 0; i < 2; ++i) {
    const int c = tid + i * 256;        // 0..511
    const int kr = c >> 3, d0 = (c & 7) * 8;
    const s16x8 v = *(const s16x8*)(V + ((size_t)(b*Sk + kt*64 + kr)*NH + h)*HD + d0);
    *(s16x8*)(&tile[kr][d0]) = v;
  }
  __syncthreads();
  #pragma unroll
  for (int i = 0; i < 2; ++i) {
    const int c = tid + i * 256;
    const int d = c >> 3, k0 = (c & 7) * 8;
    s16x8 v;
    #pragma unroll
    for (int j = 0; j < 8; ++j) v[j] = tile[k0 + j][d];
    *(s16x8*)(VT + ((size_t)(b*NH + h)*HD + d)*Sk + kt*64 + k0) = v;
  }
}

// ---------------- fused dual-context flash attention -------------------------
// Block = (q-tile 64, head, batch); 4 waves, each owns 16 q rows.
// Gate folded into P columns (softmax denom excludes gate).
__global__ __launch_bounds__(256) void attn_kernel(
    const bf16* __restrict__ Q,
    const bf16* __restrict__ K1, const bf16* __restrict__ VT1, const float* __restrict__ g1,
    const bf16* __restrict__ K2, const bf16* __restrict__ VT2, const float* __restrict__ g2,
    bf16* __restrict__ Hout)
{
  __shared__ alignas(16) bf16 pl[4][16][64];   // per-wave P tile
  const int lane = threadIdx.x & 63, wave = threadIdx.x >> 6;
  const int qt = blockIdx.x, h = blockIdx.y, b = blockIdx.z;
  const int q0 = qt * 64 + wave * 16;
  const int m16 = lane & 15, g16 = lane >> 4;

  const bf16* qrow = Q + ((size_t)(b*SQ + q0 + m16)*NH + h)*HD;
  s16x8 qf[2];
  qf[0] = *(const s16x8*)(qrow + g16 * 8);
  qf[1] = *(const s16x8*)(qrow + 32 + g16 * 8);

  float of[4][4];
  #pragma unroll
  for (int i = 0; i < 4; ++i)
    #pragma unroll
    for (int r = 0; r < 4; ++r) of[i][r] = 0.0f;

  for (int ctx = 0; ctx < 2; ++ctx) {
    const bf16* Kc = ctx ? K2 : K1;
    const bf16* VT = ctx ? VT2 : VT1;
    const float* gate = ctx ? g2 : g1;
    const int Sk = ctx ? SKT : SKV;
    const bf16* VTb = VT + (size_t)(b*NH + h) * HD * Sk;

    f32x4 o[4];
    float mx[4], l[4];
    #pragma unroll
    for (int i = 0; i < 4; ++i) {
      #pragma unroll
      for (int r = 0; r < 4; ++r) o[i][r] = 0.0f;
      mx[i] = -1e30f; l[i] = 0.0f;
    }

    for (int kv0 = 0; kv0 < Sk; kv0 += 64) {
      f32x4 s[4];
      #pragma unroll
      for (int nt = 0; nt < 4; ++nt) {
        f32x4 a;
        #pragma unroll
        for (int r = 0; r < 4; ++r) a[r] = 0.0f;
        const bf16* krow = Kc + ((size_t)(b*Sk + kv0 + nt*16 + m16)*NH + h)*HD;
        const s16x8 kf0 = *(const s16x8*)(krow + g16 * 8);
        const s16x8 kf1 = *(const s16x8*)(krow + 32 + g16 * 8);
        a = __builtin_amdgcn_mfma_f32_16x16x32_bf16(qf[0], kf0, a, 0, 0, 0);
        a = __builtin_amdgcn_mfma_f32_16x16x32_bf16(qf[1], kf1, a, 0, 0, 0);
        #pragma unroll
        for (int r = 0; r < 4; ++r) s[nt][r] = a[r] * 0.125f;
      }
      // online softmax per q-row (row lives on 16 lanes of this group)
      float alpha[4];
      #pragma unroll
      for (int r = 0; r < 4; ++r) {
        float v = fmaxf(fmaxf(s[0][r], s[1][r]), fmaxf(s[2][r], s[3][r]));
        v = fmaxf(v, __shfl_xor(v, 1));
        v = fmaxf(v, __shfl_xor(v, 2));
        v = fmaxf(v, __shfl_xor(v, 4));
        v = fmaxf(v, __shfl_xor(v, 8));
        const float mnew = fmaxf(mx[r], v);
        alpha[r] = __expf(mx[r] - mnew);
        mx[r] = mnew;
      }
      float p[4][4];
      #pragma unroll
      for (int nt = 0; nt < 4; ++nt)
        #pragma unroll
        for (int r = 0; r < 4; ++r) p[nt][r] = __expf(s[nt][r] - mx[r]);
      #pragma unroll
      for (int r = 0; r < 4; ++r) {
        float rs = p[0][r] + p[1][r] + p[2][r] + p[3][r];
        rs += __shfl_xor(rs, 1); rs += __shfl_xor(rs, 2);
        rs += __shfl_xor(rs, 4); rs += __shfl_xor(rs, 8);
        l[r] = l[r] * alpha[r] + rs;
      }
      #pragma unroll
      for (int nd = 0; nd < 4; ++nd)
        #pragma unroll
        for (int r = 0; r < 4; ++r) o[nd][r] *= alpha[r];
      // gate into P, store to LDS (bf16)
      #pragma unroll
      for (int nt = 0; nt < 4; ++nt) {
        const float gv = gate[(size_t)b * Sk + kv0 + nt*16 + m16];
        #pragma unroll
        for (int r = 0; r < 4; ++r)
          pl[wave][g16*4 + r][nt*16 + m16] = __float2bfloat16(p[nt][r] * gv);
      }
      __syncthreads();
      #pragma unroll
      for (int ks = 0; ks < 2; ++ks) {
        const s16x8 pa = *(const s16x8*)(&pl[wave][m16][ks*32 + g16*8]);
        #pragma unroll
        for (int nd = 0; nd < 4; ++nd) {
          const s16x8 vf = *(const s16x8*)(VTb + (size_t)(nd*16 + m16)*Sk + kv0 + ks*32 + g16*8);
          o[nd] = __builtin_amdgcn_mfma_f32_16x16x32_bf16(pa, vf, o[nd], 0, 0, 0);
        }
      }
      __syncthreads();
    }
    #pragma unroll
    for (int nd = 0; nd < 4; ++nd)
      #pragma unroll
      for (int r = 0; r < 4; ++r) of[nd][r] += o[nd][r] / l[r];
  }
  #pragma unroll
  for (int nd = 0; nd < 4; ++nd)
    #pragma unroll
    for (int r = 0; r < 4; ++r) {
      const int row = q0 + g16*4 + r;
      Hout[((size_t)(b*SQ + row)*NH + h)*HD + nd*16 + m16] =
          __float2bfloat16(of[nd][r]);
    }
}

// ---------------- host launch ------------------------------------------------
extern "C" void kernel_launch(void* const* d_in, const int* in_sizes, int n_in,
                              void* d_out, int out_size, void* d_ws, size_t ws_size,
                              hipStream_t stream)
{
  const float* queries = (const float*)d_in[0];
  const float* ctx_v   = (const float*)d_in[1];
  const float* ctx_t   = (const float*)d_in[2];
  const float* w_nq = (const float*)d_in[3];
  const float* w_nv = (const float*)d_in[4];
  const float* w_nt = (const float*)d_in[5];
  const float* Wq   = (const float*)d_in[6];  const float* bq   = (const float*)d_in[7];
  const float* Wk_v = (const float*)d_in[8];  const float* bk_v = (const float*)d_in[9];
  const float* Wv_v = (const float*)d_in[10]; const float* bv_v = (const float*)d_in[11];
  const float* Wk_t = (const float*)d_in[12]; const float* bk_t = (const float*)d_in[13];
  const float* Wv_t = (const float*)d_in[14]; const float* bv_t = (const float*)d_in[15];
  const float* Wg1v = (const float*)d_in[16]; const float* bg1v = (const float*)d_in[17];
  const float* Wg2v = (const float*)d_in[18]; const float* bg2v = (const float*)d_in[19];
  const float* Wg1t = (const float*)d_in[20]; const float* bg1t = (const float*)d_in[21];
  const float* Wg2t = (const float*)d_in[22]; const float* bg2t = (const float*)d_in[23];
  const float* Wo   = (const float*)d_in[24]; const float* bo   = (const float*)d_in[25];

  char* ws = (char*)d_ws;
  size_t off = 0;
  auto alloc = [&](size_t n) { void* p = ws + off; off += (n + 255) & ~(size_t)255; return p; };

  const size_t MATB = (size_t)DIM * DIM * 2;
  bf16* WqB   = (bf16*)alloc(MATB);
  bf16* WkvB  = (bf16*)alloc(MATB);
  bf16* WvvB  = (bf16*)alloc(MATB);
  bf16* WktB  = (bf16*)alloc(MATB);
  bf16* WvtB  = (bf16*)alloc(MATB);
  bf16* Wg1vB = (bf16*)alloc(MATB);
  bf16* Wg1tB = (bf16*)alloc(MATB);
  bf16* WoB   = (bf16*)alloc(MATB);
  bf16* Wg2vB = (bf16*)alloc(2048);
  bf16* Wg2tB = (bf16*)alloc(2048);

  bf16* qn  = (bf16*)alloc((size_t)BB*SQ*DIM*2);
  bf16* cv  = (bf16*)alloc((size_t)BB*SKV*DIM*2);
  bf16* ct  = (bf16*)alloc((size_t)BB*SKT*DIM*2);
  bf16* qb  = (bf16*)alloc((size_t)BB*SQ*DIM*2);
  bf16* kvB = (bf16*)alloc((size_t)BB*SKV*DIM*2);
  bf16* ktB = (bf16*)alloc((size_t)BB*SKT*DIM*2);
  bf16* vtV = (bf16*)alloc((size_t)BB*SKV*DIM*2);
  bf16* vtT = (bf16*)alloc((size_t)BB*SKT*DIM*2);
  bf16* vScr  = (bf16*)alloc((size_t)BB*SKV*DIM*2);   // reused vis then text
  bf16* g1Scr = (bf16*)alloc((size_t)BB*SKV*DIM*2);   // reused vis then text
  float* gateV = (float*)alloc((size_t)BB*SKV*4);
  float* gateT = (float*)alloc((size_t)BB*SKT*4);
  bf16* hB  = (bf16*)alloc((size_t)BB*SQ*DIM*2);
  (void)ws_size; (void)n_in; (void)in_sizes; (void)out_size;

  // 1. weight casts
  CastArgs ca;
  const float* wsrc[10] = {Wq, Wk_v, Wv_v, Wk_t, Wv_t, Wg1v, Wg1t, Wo, Wg2v, Wg2t};
  bf16* wdst[10] = {WqB, WkvB, WvvB, WktB, WvtB, Wg1vB, Wg1tB, WoB, Wg2vB, Wg2tB};
  for (int i = 0; i < 10; ++i) {
    ca.src[i] = wsrc[i]; ca.dst[i] = wdst[i];
    ca.n[i] = (i < 8) ? DIM * DIM : DIM;
  }
  cast_kernel<<<dim3(1024, 10), 256, 0, stream>>>(ca);

  // 2. RMSNorms
  NormArgs na;
  na.x[0] = queries; na.x[1] = ctx_v; na.x[2] = ctx_t;
  na.w[0] = w_nq;    na.w[1] = w_nv;  na.w[2] = w_nt;
  na.y[0] = qn;      na.y[1] = cv;    na.y[2] = ct;
  na.rows[0] = BB*SQ; na.rows[1] = BB*SKV; na.rows[2] = BB*SKT;
  rmsnorm_kernel<<<dim3(BB*SKV, 3), 256, 0, stream>>>(na);

  // 3. projections (visual)
  gemm128<0><<<dim3(BB*SQ/128, 8),  256, 0, stream>>>(qn, WqB,  bq,  nullptr, qb,   nullptr);
  gemm128<0><<<dim3(BB*SKV/128, 8), 256, 0, stream>>>(cv, WkvB, bk_v, nullptr, kvB,  nullptr);
  gemm128<0><<<dim3(BB*SKV/128, 8), 256, 0, stream>>>(cv, WvvB, bv_v, nullptr, vScr, nullptr);
  gemm128<1><<<dim3(BB*SKV/128, 8), 256, 0, stream>>>(cv, Wg1vB, bg1v, nullptr, g1Scr, nullptr);
  gate_kernel<<<dim3(BB*SKV/4), 256, 0, stream>>>(g1Scr, Wg2vB, bg2v, gateV, BB*SKV);
  vtrans_kernel<<<dim3(SKV/64, NH, BB), 256, 0, stream>>>(vScr, vtV, SKV);

  // 4. projections (text)
  gemm128<0><<<dim3(BB*SKT/128, 8), 256, 0, stream>>>(ct, WktB, bk_t, nullptr, ktB,  nullptr);
  gemm128<0><<<dim3(BB*SKT/128, 8), 256, 0, stream>>>(ct, WvtB, bv_t, nullptr, vScr, nullptr);
  gemm128<1><<<dim3(BB*SKT/128, 8), 256, 0, stream>>>(ct, Wg1tB, bg1t, nullptr, g1Scr, nullptr);
  gate_kernel<<<dim3(BB*SKT/4), 256, 0, stream>>>(g1Scr, Wg2tB, bg2t, gateT, BB*SKT);
  vtrans_kernel<<<dim3(SKT/64, NH, BB), 256, 0, stream>>>(vScr, vtT, SKT);

  // 5. fused dual-context attention
  attn_kernel<<<dim3(SQ/64, NH, BB), 256, 0, stream>>>(
      qb, kvB, vtV, gateV, ktB, vtT, gateT, hB);

  // 6. output projection + residual (f32 out)
  gemm128<2><<<dim3(BB*SQ/128, 8), 256, 0, stream>>>(hB, WoB, bo, queries, nullptr, (float*)d_out);
}

// Round 2
// 267.802 us; speedup vs baseline: 1.5439x; 1.5439x over previous
//
#include <hip/hip_runtime.h>
#include <hip/hip_bf16.h>

typedef __attribute__((ext_vector_type(4))) float f32x4;
typedef __attribute__((ext_vector_type(8))) short s16x8;
using bf16 = __hip_bfloat16;

static constexpr int BB  = 4;
static constexpr int SQ  = 512;
static constexpr int SKV = 2048;
static constexpr int SKT = 512;
static constexpr int DIM = 1024;
static constexpr int NH  = 16;
static constexpr int HD  = 64;

__device__ __forceinline__ float b2f(short s) {
  unsigned int u = ((unsigned int)(unsigned short)s) << 16;
  float f; __builtin_memcpy(&f, &u, 4); return f;
}
__device__ __forceinline__ short f2s(float f) {
  bf16 h = __float2bfloat16(f); short s; __builtin_memcpy(&s, &h, 2); return s;
}

__device__ __forceinline__ void gload16(const void* g, void* l) {
  __builtin_amdgcn_global_load_lds(
      (const __attribute__((address_space(1))) void*)g,
      (__attribute__((address_space(3))) void*)l, 16, 0, 0);
}

// ---------------- weight cast f32 -> bf16 (batched via grid.y) --------------
struct CastArgs { const float* src[10]; bf16* dst[10]; int n[10]; };
__global__ __launch_bounds__(256) void cast_kernel(CastArgs a) {
  const int y = blockIdx.y;
  const int n = a.n[y];
  const int i = (blockIdx.x * 256 + threadIdx.x) * 4;
  if (i >= n) return;
  const float4 v = *(const float4*)(a.src[y] + i);
  bf16* d = a.dst[y] + i;
  d[0] = __float2bfloat16(v.x); d[1] = __float2bfloat16(v.y);
  d[2] = __float2bfloat16(v.z); d[3] = __float2bfloat16(v.w);
}

// ---------------- RMSNorm (f32 in, bf16 out), one block per row -------------
struct NormArgs { const float* x[3]; const float* w[3]; bf16* y[3]; int rows[3]; };
__global__ __launch_bounds__(256) void rmsnorm_kernel(NormArgs a) {
  const int t = blockIdx.y, row = blockIdx.x;
  if (row >= a.rows[t]) return;
  const float* x = a.x[t] + (size_t)row * DIM;
  const float4 v = *(const float4*)(x + threadIdx.x * 4);
  float ss = v.x*v.x + v.y*v.y + v.z*v.z + v.w*v.w;
  #pragma unroll
  for (int m = 32; m >= 1; m >>= 1) ss += __shfl_xor(ss, m);
  __shared__ float red[4];
  if ((threadIdx.x & 63) == 0) red[threadIdx.x >> 6] = ss;
  __syncthreads();
  ss = red[0] + red[1] + red[2] + red[3];
  const float sc = rsqrtf(ss * (1.0f / DIM) + 1.1920928955078125e-07f);
  const float4 w = *(const float4*)(a.w[t] + threadIdx.x * 4);
  bf16* y = a.y[t] + (size_t)row * DIM + threadIdx.x * 4;
  y[0] = __float2bfloat16(v.x * sc * w.x);
  y[1] = __float2bfloat16(v.y * sc * w.y);
  y[2] = __float2bfloat16(v.z * sc * w.z);
  y[3] = __float2bfloat16(v.w * sc * w.w);
}

// ---------------- GEMM: C = act(A @ W^T + bias), slot-batched ----------------
// 128x128 tile, BK=64, double-buffered LDS w/ XOR swizzle, 1 barrier / K-step.
// epi 0: bf16; 1: silu bf16; 2: f32 + resid; 3: bf16 * 0.125 (attn scale).
struct GSlot { const bf16* A; const bf16* W; const float* bias;
               const float* resid; bf16* Cb; float* Cf; int epi; };
struct GArgs { GSlot s[4]; };

__global__ __launch_bounds__(256) void gemm_dbuf(GArgs a) {
  constexpr int K = DIM;
  __shared__ alignas(16) char sA[2][16384];
  __shared__ alignas(16) char sB[2][16384];
  const GSlot S = a.s[blockIdx.z];
  const int tid = threadIdx.x, lane = tid & 63, wave = tid >> 6;
  const int bm = blockIdx.x, bn = blockIdx.y;
  const int wm = wave >> 1, wn = wave & 1;
  const int m16 = lane & 15, g16 = lane >> 4;

  f32x4 acc[4][4];
  #pragma unroll
  for (int i = 0; i < 4; ++i)
    #pragma unroll
    for (int j = 0; j < 4; ++j)
      #pragma unroll
      for (int r = 0; r < 4; ++r) acc[i][j][r] = 0.0f;

  const bf16* Ab = S.A + (size_t)bm * 128 * K;
  const bf16* Wb = S.W + (size_t)bn * 128 * K;
  const int lrow = lane >> 3, lgr = lane & 7;
  const int sg = lgr ^ (lrow & 7);          // pre-swizzled source granule

  auto stage = [&](int k0, int buf) {
    #pragma unroll
    for (int rr = 0; rr < 4; ++rr) {
      const int chunk = rr * 4 + wave;      // wave-uniform
      const int row = chunk * 8 + lrow;
      const size_t so = (size_t)row * K + k0 + sg * 8;
      gload16(Ab + so, &sA[buf][chunk * 1024]);
      gload16(Wb + so, &sB[buf][chunk * 1024]);
    }
  };

  stage(0, 0);
  __syncthreads();
  int cur = 0;
  for (int t = 0; t < K / 64; ++t) {
    if (t + 1 < K / 64) stage((t + 1) * 64, cur ^ 1);
    s16x8 af[4][2], bfr[4][2];
    #pragma unroll
    for (int mi = 0; mi < 4; ++mi) {
      const int row = wm * 64 + mi * 16 + m16;
      #pragma unroll
      for (int h2 = 0; h2 < 2; ++h2)
        af[mi][h2] = *(const s16x8*)(&sA[cur][row * 128 + (((h2 * 4 + g16)) ^ (m16 & 7)) * 16]);
    }
    #pragma unroll
    for (int ni = 0; ni < 4; ++ni) {
      const int row = wn * 64 + ni * 16 + m16;
      #pragma unroll
      for (int h2 = 0; h2 < 2; ++h2)
        bfr[ni][h2] = *(const s16x8*)(&sB[cur][row * 128 + (((h2 * 4 + g16)) ^ (m16 & 7)) * 16]);
    }
    #pragma unroll
    for (int mi = 0; mi < 4; ++mi)
      #pragma unroll
      for (int ni = 0; ni < 4; ++ni) {
        acc[mi][ni] = __builtin_amdgcn_mfma_f32_16x16x32_bf16(af[mi][0], bfr[ni][0], acc[mi][ni], 0, 0, 0);
        acc[mi][ni] = __builtin_amdgcn_mfma_f32_16x16x32_bf16(af[mi][1], bfr[ni][1], acc[mi][ni], 0, 0, 0);
      }
    __syncthreads();
    cur ^= 1;
  }

  const int r0 = bm * 128 + wm * 64, c0 = bn * 128 + wn * 64;
  #pragma unroll
  for (int ni = 0; ni < 4; ++ni) {
    const int col = c0 + ni * 16 + m16;
    const float bv = S.bias[col];
    #pragma unroll
    for (int mi = 0; mi < 4; ++mi) {
      const int rowb = r0 + mi * 16 + g16 * 4;
      #pragma unroll
      for (int r = 0; r < 4; ++r) {
        float v = acc[mi][ni][r] + bv;
        const size_t idx = (size_t)(rowb + r) * DIM + col;
        if (S.epi == 1)      { v = v / (1.0f + __expf(-v)); S.Cb[idx] = __float2bfloat16(v); }
        else if (S.epi == 2) { S.Cf[idx] = v + S.resid[idx]; }
        else if (S.epi == 3) { S.Cb[idx] = __float2bfloat16(v * 0.125f); }
        else                 { S.Cb[idx] = __float2bfloat16(v); }
      }
    }
  }
}

// ---------------- gate GEMV: gate = sigmoid(g1 . w2 + b2), wave per row -----
__global__ __launch_bounds__(256) void gate_kernel(
    const bf16* __restrict__ g1, const bf16* __restrict__ w2,
    const float* __restrict__ b2, float* __restrict__ gate, int rows)
{
  const int lane = threadIdx.x & 63, wave = threadIdx.x >> 6;
  const int row = blockIdx.x * 4 + wave;
  if (row >= rows) return;
  const bf16* x = g1 + (size_t)row * DIM;
  float sum = 0.0f;
  #pragma unroll
  for (int c = 0; c < 2; ++c) {
    const int i0 = c * 512 + lane * 8;
    const s16x8 xv = *(const s16x8*)(x + i0);
    const s16x8 wv = *(const s16x8*)(w2 + i0);
    #pragma unroll
    for (int j = 0; j < 8; ++j) sum += b2f(xv[j]) * b2f(wv[j]);
  }
  #pragma unroll
  for (int m = 32; m >= 1; m >>= 1) sum += __shfl_xor(sum, m);
  if (lane == 0) gate[row] = 1.0f / (1.0f + __expf(-(sum + b2[0])));
}

// ------- V transpose + gate fold: [B,Sk,H,64] * g[B,Sk] -> [B*H,64,Sk] ------
__global__ __launch_bounds__(256) void vtrans_kernel(
    const bf16* __restrict__ V, const float* __restrict__ gate,
    bf16* __restrict__ VT, int Sk)
{
  __shared__ alignas(16) short tile[64][72];
  const int kt = blockIdx.x, h = blockIdx.y, b = blockIdx.z;
  const int tid = threadIdx.x;
  #pragma unroll
  for (int i = 0; i < 2; ++i) {
    const int c = tid + i * 256;        // 0..511
    const int kr = c >> 3, d0 = (c & 7) * 8;
    const float g = gate[(size_t)b * Sk + kt * 64 + kr];
    const s16x8 v = *(const s16x8*)(V + ((size_t)(b*Sk + kt*64 + kr)*NH + h)*HD + d0);
    #pragma unroll
    for (int j = 0; j < 8; ++j) tile[kr][d0 + j] = f2s(b2f(v[j]) * g);
  }
  __syncthreads();
  #pragma unroll
  for (int i = 0; i < 2; ++i) {
    const int c = tid + i * 256;
    const int d = c >> 3, k0 = (c & 7) * 8;
    s16x8 v;
    #pragma unroll
    for (int j = 0; j < 8; ++j) v[j] = tile[k0 + j][d];
    *(s16x8*)(VT + ((size_t)(b*NH + h)*HD + d)*Sk + kt*64 + k0) = v;
  }
}

// ---------------- fused dual-context flash attention -------------------------
// Block = (head*batch in x for XCD locality, q-tile in y); 4 waves x 16 q rows.
// K/VT staged in LDS (double-buffered global_load_lds, XOR swizzle), gate
// pre-folded into VT, 1/8 scale pre-folded into Q.
__global__ __launch_bounds__(256) void attn_kernel(
    const bf16* __restrict__ Q,
    const bf16* __restrict__ K1, const bf16* __restrict__ VT1,
    const bf16* __restrict__ K2, const bf16* __restrict__ VT2,
    bf16* __restrict__ Hout)
{
  __shared__ alignas(16) char sK[2][8192];
  __shared__ alignas(16) char sVT[2][8192];
  __shared__ alignas(16) short sP[4][1024];
  const int tid = threadIdx.x, lane = tid & 63, wave = tid >> 6;
  const int hb = blockIdx.x;
  const int h = hb & 15, b = hb >> 4;
  const int qt = blockIdx.y;
  const int q0 = qt * 64 + wave * 16;
  const int m16 = lane & 15, g16 = lane >> 4;

  const bf16* qrow = Q + ((size_t)(b*SQ + q0 + m16)*NH + h)*HD;
  const s16x8 qf0 = *(const s16x8*)(qrow + g16 * 8);
  const s16x8 qf1 = *(const s16x8*)(qrow + 32 + g16 * 8);

  const bf16* VT1b = VT1 + (size_t)(b*NH + h) * HD * SKV;
  const bf16* VT2b = VT2 + (size_t)(b*NH + h) * HD * SKT;

  // staging: 64 rows x 64 cols bf16 per tile; pre-swizzled global source
  auto stage = [&](const bf16* Kc, const bf16* VTb, int Sk, int kv0, int buf) {
    #pragma unroll
    for (int rr = 0; rr < 2; ++rr) {
      const int idx = rr * 256 + tid;       // 0..511
      const int row = idx >> 3;             // 0..63
      const int sgr = (idx & 7) ^ (row & 7);
      gload16(Kc + ((size_t)(b*Sk + kv0 + row)*NH + h)*HD + sgr*8,
              &sK[buf][rr * 4096 + wave * 1024]);
      gload16(VTb + (size_t)row * Sk + kv0 + sgr*8,
              &sVT[buf][rr * 4096 + wave * 1024]);
    }
  };

  float of[4][4];
  #pragma unroll
  for (int i = 0; i < 4; ++i)
    #pragma unroll
    for (int r = 0; r < 4; ++r) of[i][r] = 0.0f;

  f32x4 o[4]; float mx[4], l[4];
  auto reset_state = [&]() {
    #pragma unroll
    for (int i = 0; i < 4; ++i) {
      #pragma unroll
      for (int r = 0; r < 4; ++r) o[i][r] = 0.0f;
      mx[i] = -1e30f; l[i] = 0.0f;
    }
  };
  auto flush_state = [&]() {
    #pragma unroll
    for (int nd = 0; nd < 4; ++nd)
      #pragma unroll
      for (int r = 0; r < 4; ++r) of[nd][r] += o[nd][r] / l[r];
  };

  auto chunk_compute = [&](int buf) {
    // QK^T from staged K
    f32x4 s4[4];
    #pragma unroll
    for (int nt = 0; nt < 4; ++nt) {
      const char* kr = &sK[buf][(nt * 16 + m16) * 128];
      const s16x8 kf0 = *(const s16x8*)(kr + ((g16    ) ^ (m16 & 7)) * 16);
      const s16x8 kf1 = *(const s16x8*)(kr + ((4 + g16) ^ (m16 & 7)) * 16);
      f32x4 a; a[0]=0; a[1]=0; a[2]=0; a[3]=0;
      a = __builtin_amdgcn_mfma_f32_16x16x32_bf16(qf0, kf0, a, 0, 0, 0);
      a = __builtin_amdgcn_mfma_f32_16x16x32_bf16(qf1, kf1, a, 0, 0, 0);
      s4[nt] = a;
    }
    // online softmax (rows on g16*4+r, kv on nt*16+m16)
    float alpha[4];
    #pragma unroll
    for (int r = 0; r < 4; ++r) {
      float v = fmaxf(fmaxf(s4[0][r], s4[1][r]), fmaxf(s4[2][r], s4[3][r]));
      v = fmaxf(v, __shfl_xor(v, 1));
      v = fmaxf(v, __shfl_xor(v, 2));
      v = fmaxf(v, __shfl_xor(v, 4));
      v = fmaxf(v, __shfl_xor(v, 8));
      const float mnew = fmaxf(mx[r], v);
      alpha[r] = __expf(mx[r] - mnew);
      mx[r] = mnew;
    }
    float p[4][4];
    #pragma unroll
    for (int nt = 0; nt < 4; ++nt)
      #pragma unroll
      for (int r = 0; r < 4; ++r) p[nt][r] = __expf(s4[nt][r] - mx[r]);
    #pragma unroll
    for (int r = 0; r < 4; ++r) {
      float rs = p[0][r] + p[1][r] + p[2][r] + p[3][r];
      rs += __shfl_xor(rs, 1); rs += __shfl_xor(rs, 2);
      rs += __shfl_xor(rs, 4); rs += __shfl_xor(rs, 8);
      l[r] = l[r] * alpha[r] + rs;
    }
    #pragma unroll
    for (int nd = 0; nd < 4; ++nd)
      #pragma unroll
      for (int r = 0; r < 4; ++r) o[nd][r] *= alpha[r];
    // P -> LDS (swizzled), wave-local
    #pragma unroll
    for (int nt = 0; nt < 4; ++nt)
      #pragma unroll
      for (int r = 0; r < 4; ++r) {
        const int prow = g16 * 4 + r;
        const int pg = (nt * 2 + (m16 >> 3)) ^ (prow & 7);
        sP[wave][prow * 64 + pg * 8 + (m16 & 7)] = f2s(p[nt][r]);
      }
    // PV from staged VT
    #pragma unroll
    for (int ks = 0; ks < 2; ++ks) {
      const int pg = (ks * 4 + g16) ^ (m16 & 7);
      const s16x8 pa = *(const s16x8*)(&sP[wave][m16 * 64 + pg * 8]);
      #pragma unroll
      for (int nd = 0; nd < 4; ++nd) {
        const s16x8 vf = *(const s16x8*)(&sVT[buf][(nd * 16 + m16) * 128 + pg * 16]);
        o[nd] = __builtin_amdgcn_mfma_f32_16x16x32_bf16(pa, vf, o[nd], 0, 0, 0);
      }
    }
  };

  stage(K1, VT1b, SKV, 0, 0);
  __syncthreads();
  int cur = 0;

  reset_state();
  constexpr int NC1 = SKV / 64, NC2 = SKT / 64;
  for (int c = 0; c < NC1; ++c) {
    if (c + 1 < NC1) stage(K1, VT1b, SKV, (c + 1) * 64, cur ^ 1);
    else             stage(K2, VT2b, SKT, 0, cur ^ 1);
    chunk_compute(cur);
    __syncthreads();
    cur ^= 1;
  }
  flush_state();

  reset_state();
  for (int c = 0; c < NC2; ++c) {
    if (c + 1 < NC2) stage(K2, VT2b, SKT, (c + 1) * 64, cur ^ 1);
    chunk_compute(cur);
    __syncthreads();
    cur ^= 1;
  }
  flush_state();

  #pragma unroll
  for (int nd = 0; nd < 4; ++nd)
    #pragma unroll
    for (int r = 0; r < 4; ++r) {
      const int row = q0 + g16 * 4 + r;
      Hout[((size_t)(b*SQ + row)*NH + h)*HD + nd*16 + m16] =
          __float2bfloat16(of[nd][r]);
    }
}

// ---------------- host launch ------------------------------------------------
extern "C" void kernel_launch(void* const* d_in, const int* in_sizes, int n_in,
                              void* d_out, int out_size, void* d_ws, size_t ws_size,
                              hipStream_t stream)
{
  const float* queries = (const float*)d_in[0];
  const float* ctx_v   = (const float*)d_in[1];
  const float* ctx_t   = (const float*)d_in[2];
  const float* w_nq = (const float*)d_in[3];
  const float* w_nv = (const float*)d_in[4];
  const float* w_nt = (const float*)d_in[5];
  const float* Wq   = (const float*)d_in[6];  const float* bq   = (const float*)d_in[7];
  const float* Wk_v = (const float*)d_in[8];  const float* bk_v = (const float*)d_in[9];
  const float* Wv_v = (const float*)d_in[10]; const float* bv_v = (const float*)d_in[11];
  const float* Wk_t = (const float*)d_in[12]; const float* bk_t = (const float*)d_in[13];
  const float* Wv_t = (const float*)d_in[14]; const float* bv_t = (const float*)d_in[15];
  const float* Wg1v = (const float*)d_in[16]; const float* bg1v = (const float*)d_in[17];
  const float* Wg2v = (const float*)d_in[18]; const float* bg2v = (const float*)d_in[19];
  const float* Wg1t = (const float*)d_in[20]; const float* bg1t = (const float*)d_in[21];
  const float* Wg2t = (const float*)d_in[22]; const float* bg2t = (const float*)d_in[23];
  const float* Wo   = (const float*)d_in[24]; const float* bo   = (const float*)d_in[25];

  char* ws = (char*)d_ws;
  size_t off = 0;
  auto alloc = [&](size_t n) { void* p = ws + off; off += (n + 255) & ~(size_t)255; return p; };

  const size_t MATB = (size_t)DIM * DIM * 2;
  bf16* WqB   = (bf16*)alloc(MATB);
  bf16* WkvB  = (bf16*)alloc(MATB);
  bf16* WvvB  = (bf16*)alloc(MATB);
  bf16* WktB  = (bf16*)alloc(MATB);
  bf16* WvtB  = (bf16*)alloc(MATB);
  bf16* Wg1vB = (bf16*)alloc(MATB);
  bf16* Wg1tB = (bf16*)alloc(MATB);
  bf16* WoB   = (bf16*)alloc(MATB);
  bf16* Wg2vB = (bf16*)alloc(2048);
  bf16* Wg2tB = (bf16*)alloc(2048);

  bf16* qn  = (bf16*)alloc((size_t)BB*SQ*DIM*2);
  bf16* cv  = (bf16*)alloc((size_t)BB*SKV*DIM*2);
  bf16* ct  = (bf16*)alloc((size_t)BB*SKT*DIM*2);
  bf16* qb  = (bf16*)alloc((size_t)BB*SQ*DIM*2);
  bf16* kvB = (bf16*)alloc((size_t)BB*SKV*DIM*2);
  bf16* ktB = (bf16*)alloc((size_t)BB*SKT*DIM*2);
  bf16* vtV = (bf16*)alloc((size_t)BB*SKV*DIM*2);
  bf16* vtT = (bf16*)alloc((size_t)BB*SKT*DIM*2);
  bf16* vScr  = (bf16*)alloc((size_t)BB*SKV*DIM*2);   // reused vis then text
  bf16* g1Scr = (bf16*)alloc((size_t)BB*SKV*DIM*2);   // reused vis then text
  float* gateV = (float*)alloc((size_t)BB*SKV*4);
  float* gateT = (float*)alloc((size_t)BB*SKT*4);
  bf16* hB  = (bf16*)alloc((size_t)BB*SQ*DIM*2);
  (void)ws_size; (void)n_in; (void)in_sizes; (void)out_size;

  // 1. weight casts
  CastArgs ca;
  const float* wsrc[10] = {Wq, Wk_v, Wv_v, Wk_t, Wv_t, Wg1v, Wg1t, Wo, Wg2v, Wg2t};
  bf16* wdst[10] = {WqB, WkvB, WvvB, WktB, WvtB, Wg1vB, Wg1tB, WoB, Wg2vB, Wg2tB};
  for (int i = 0; i < 10; ++i) {
    ca.src[i] = wsrc[i]; ca.dst[i] = wdst[i];
    ca.n[i] = (i < 8) ? DIM * DIM : DIM;
  }
  cast_kernel<<<dim3(1024, 10), 256, 0, stream>>>(ca);

  // 2. RMSNorms
  NormArgs na;
  na.x[0] = queries; na.x[1] = ctx_v; na.x[2] = ctx_t;
  na.w[0] = w_nq;    na.w[1] = w_nv;  na.w[2] = w_nt;
  na.y[0] = qn;      na.y[1] = cv;    na.y[2] = ct;
  na.rows[0] = BB*SQ; na.rows[1] = BB*SKV; na.rows[2] = BB*SKT;
  rmsnorm_kernel<<<dim3(BB*SKV, 3), 256, 0, stream>>>(na);

  // 3. visual trio (K, V, G1) in one slot-batched launch
  GArgs gv{};
  gv.s[0] = {cv, WkvB,  bk_v, nullptr, kvB,   nullptr, 0};
  gv.s[1] = {cv, WvvB,  bv_v, nullptr, vScr,  nullptr, 0};
  gv.s[2] = {cv, Wg1vB, bg1v, nullptr, g1Scr, nullptr, 1};
  gv.s[3] = gv.s[0];
  gemm_dbuf<<<dim3(BB*SKV/128, 8, 3), 256, 0, stream>>>(gv);
  gate_kernel<<<dim3(BB*SKV/4), 256, 0, stream>>>(g1Scr, Wg2vB, bg2v, gateV, BB*SKV);
  vtrans_kernel<<<dim3(SKV/64, NH, BB), 256, 0, stream>>>(vScr, gateV, vtV, SKV);

  // 4. Q (pre-scaled by 1/8) + text trio in one slot-batched launch
  GArgs gm{};
  gm.s[0] = {qn, WqB,   bq,   nullptr, qb,    nullptr, 3};
  gm.s[1] = {ct, WktB,  bk_t, nullptr, ktB,   nullptr, 0};
  gm.s[2] = {ct, WvtB,  bv_t, nullptr, vScr,  nullptr, 0};
  gm.s[3] = {ct, Wg1tB, bg1t, nullptr, g1Scr, nullptr, 1};
  gemm_dbuf<<<dim3(BB*SKT/128, 8, 4), 256, 0, stream>>>(gm);
  gate_kernel<<<dim3(BB*SKT/4), 256, 0, stream>>>(g1Scr, Wg2tB, bg2t, gateT, BB*SKT);
  vtrans_kernel<<<dim3(SKT/64, NH, BB), 256, 0, stream>>>(vScr, gateT, vtT, SKT);

  // 5. fused dual-context attention (gate folded into VT, scale folded into Q)
  attn_kernel<<<dim3(NH*BB, SQ/64), 256, 0, stream>>>(qb, kvB, vtV, ktB, vtT, hB);

  // 6. output projection + residual (f32 out)
  GArgs go{};
  go.s[0] = {hB, WoB, bo, queries, nullptr, (float*)d_out, 2};
  go.s[1] = go.s[0]; go.s[2] = go.s[0]; go.s[3] = go.s[0];
  gemm_dbuf<<<dim3(BB*SQ/128, 8, 1), 256, 0, stream>>>(go);
}